// Round 1
// baseline (1544.801 us; speedup 1.0000x reference)
//
#include <hip/hip_runtime.h>

// GAT (3 layers, heads=1) + virtual-node MLP on MI355X.
// Structure: CSR build (hist/scan/scatter) -> per layer {project, aggregate}
// -> output GEMM + per-graph pooled VN MLP.

constexpr int D = 64;

__device__ __forceinline__ float lrelu(float v, float s) { return v >= 0.f ? v : v * s; }

// ---------------- CSR build ----------------

__global__ void hist_kernel(const int* __restrict__ ei, int* __restrict__ deg, int E, int N) {
  int i = blockIdx.x * blockDim.x + threadIdx.x;
  if (i >= E + N) return;
  int d = (i < E) ? ei[E + i] : (i - E);  // row 1 of edge_index = dst; self-loops appended
  atomicAdd(&deg[d], 1);
}

__global__ void scan_kernel(const int* __restrict__ deg, int* __restrict__ row_ptr, int n) {
  __shared__ int partial[1024];
  int t = threadIdx.x;
  int chunk = (n + 1023) >> 10;
  int beg = min(t * chunk, n);
  int end = min(beg + chunk, n);
  int s = 0;
  for (int i = beg; i < end; ++i) s += deg[i];
  partial[t] = s;
  __syncthreads();
  for (int off = 1; off < 1024; off <<= 1) {
    int v = (t >= off) ? partial[t - off] : 0;
    __syncthreads();
    partial[t] += v;
    __syncthreads();
  }
  int run = (t == 0) ? 0 : partial[t - 1];
  for (int i = beg; i < end; ++i) { row_ptr[i] = run; run += deg[i]; }
  if (end == n && beg < n) row_ptr[n] = run;
}

__global__ void scatter_kernel(const int* __restrict__ ei, const int* __restrict__ row_ptr,
                               int* __restrict__ cursor, int* __restrict__ csr, int E, int N) {
  int i = blockIdx.x * blockDim.x + threadIdx.x;
  if (i >= E + N) return;
  int s, d;
  if (i < E) { s = ei[i]; d = ei[E + i]; } else { s = d = i - E; }
  int pos = atomicAdd(&cursor[d], 1);
  csr[row_ptr[d] + pos] = s;
}

// ---------------- projection: h = x @ W, s_src = h.a_src, s_dst = h.a_dst ----------------

__global__ __launch_bounds__(256) void project_kernel(
    const float* __restrict__ x, const float* __restrict__ W,
    const float* __restrict__ a_src, const float* __restrict__ a_dst,
    float* __restrict__ h, float* __restrict__ s_src, float* __restrict__ s_dst, int N) {
  __shared__ float Wl[D * D];
  int t = threadIdx.x;
  for (int i = t; i < D * D; i += 256) Wl[i] = W[i];
  __syncthreads();
  int lane = t & 63;
  int warp = t >> 6;
  float asv = a_src[lane], adv = a_dst[lane];
  int w = blockIdx.x * 4 + warp;
  int nw = gridDim.x * 4;
  for (int r = w; r < N; r += nw) {
    float xv = x[(size_t)r * D + lane];
    float acc = 0.f;
#pragma unroll
    for (int k = 0; k < D; ++k) acc = fmaf(__shfl(xv, k), Wl[k * D + lane], acc);
    h[(size_t)r * D + lane] = acc;
    float ts = acc * asv, td = acc * adv;
#pragma unroll
    for (int off = 32; off; off >>= 1) { ts += __shfl_xor(ts, off); td += __shfl_xor(td, off); }
    if (lane == 0) { s_src[r] = ts; s_dst[r] = td; }
  }
}

// final projection with bias, no attention dots
__global__ __launch_bounds__(256) void out_project_kernel(
    const float* __restrict__ x, const float* __restrict__ W, const float* __restrict__ b,
    float* __restrict__ out, int N) {
  __shared__ float Wl[D * D];
  int t = threadIdx.x;
  for (int i = t; i < D * D; i += 256) Wl[i] = W[i];
  __syncthreads();
  int lane = t & 63;
  int warp = t >> 6;
  float bv = b[lane];
  int w = blockIdx.x * 4 + warp;
  int nw = gridDim.x * 4;
  for (int r = w; r < N; r += nw) {
    float xv = x[(size_t)r * D + lane];
    float acc = bv;
#pragma unroll
    for (int k = 0; k < D; ++k) acc = fmaf(__shfl(xv, k), Wl[k * D + lane], acc);
    out[(size_t)r * D + lane] = acc;
  }
}

// ---------------- fused attention softmax + weighted aggregation ----------------
// wave per dst node; lane = feature dim. alpha-normalization deferred to the end:
// out = (sum_j p_j h[src_j]) / (sum_j p_j + 1e-16) + b, then LeakyReLU(0.01).

__global__ __launch_bounds__(256) void aggregate_kernel(
    const float* __restrict__ h, const float* __restrict__ s_src, const float* __restrict__ s_dst,
    const int* __restrict__ row_ptr, const int* __restrict__ csr,
    const float* __restrict__ bias, float* __restrict__ xout, int N) {
  int w = (blockIdx.x * blockDim.x + threadIdx.x) >> 6;
  int lane = threadIdx.x & 63;
  if (w >= N) return;
  int beg = row_ptr[w], end = row_ptr[w + 1];
  float sd = s_dst[w];
  // pass 1: segment max of LeakyReLU(0.2) logits
  float m = -3.4e38f;
  for (int base = beg; base < end; base += 64) {
    int idx = base + lane;
    float e = -3.4e38f;
    if (idx < end) e = lrelu(s_src[csr[idx]] + sd, 0.2f);
    m = fmaxf(m, e);
  }
#pragma unroll
  for (int off = 32; off; off >>= 1) m = fmaxf(m, __shfl_xor(m, off));
  // pass 2: p = exp(e - m); acc += p * h[src]; denom += p
  float denom = 0.f, acc = 0.f;
  for (int base = beg; base < end; base += 64) {
    int idx = base + lane;
    int s = 0;
    float p = 0.f;
    if (idx < end) {
      s = csr[idx];
      p = __expf(lrelu(s_src[s] + sd, 0.2f) - m);
    }
    denom += p;
    int cnt = min(64, end - base);
    for (int k = 0; k < cnt; ++k) {
      float pk = __shfl(p, k);
      int sk = __shfl(s, k);
      acc = fmaf(pk, h[(size_t)sk * D + lane], acc);
    }
  }
#pragma unroll
  for (int off = 32; off; off >>= 1) denom += __shfl_xor(denom, off);
  float o = acc / (denom + 1e-16f) + bias[lane];
  xout[(size_t)w * D + lane] = lrelu(o, 0.01f);
}

// ---------------- virtual node: per-graph pool (batch is sorted) + 4-layer MLP ----------------

__device__ __forceinline__ float mlp64(float v, const float* __restrict__ W,
                                       const float* __restrict__ b, int lane) {
  float u = b[lane];
#pragma unroll
  for (int k = 0; k < D; ++k) u = fmaf(__shfl(v, k), W[k * D + lane], u);
  return fmaxf(u, 0.f);
}

__global__ __launch_bounds__(64) void vn_kernel(
    const float* __restrict__ xa, const int* __restrict__ batch, int N,
    const float* __restrict__ vn_emb,
    const float* __restrict__ Wm1, const float* __restrict__ bm1,
    const float* __restrict__ Wm2, const float* __restrict__ bm2,
    const float* __restrict__ Wf1, const float* __restrict__ bf1,
    const float* __restrict__ Wf2, const float* __restrict__ bf2,
    float* __restrict__ out) {
  int g = blockIdx.x;
  int lane = threadIdx.x;
  // lower_bound(g), lower_bound(g+1) in sorted batch
  int lo = 0, hi = N;
  while (lo < hi) { int mid = (lo + hi) >> 1; if (batch[mid] < g) lo = mid + 1; else hi = mid; }
  int beg = lo;
  hi = N;
  while (lo < hi) { int mid = (lo + hi) >> 1; if (batch[mid] < g + 1) lo = mid + 1; else hi = mid; }
  int end = lo;
  float acc = 0.f;
  for (int r = beg; r < end; ++r) acc += xa[(size_t)r * D + lane];
  float v = acc + vn_emb[lane];
  v = mlp64(v, Wm1, bm1, lane);
  v = mlp64(v, Wm2, bm2, lane);
  v = mlp64(v, Wf1, bf1, lane);
  v = mlp64(v, Wf2, bf2, lane);
  out[(size_t)g * D + lane] = v;
}

// ---------------- launch ----------------

extern "C" void kernel_launch(void* const* d_in, const int* in_sizes, int n_in,
                              void* d_out, int out_size, void* d_ws, size_t ws_size,
                              hipStream_t stream) {
  const float* x = (const float*)d_in[0];
  const int* ei = (const int*)d_in[1];
  const int* batch = (const int*)d_in[2];
  const int N = in_sizes[0] / D;
  const int E = in_sizes[1] / 2;
  const int G = 64;

  const float* W[3] = {(const float*)d_in[4], (const float*)d_in[8], (const float*)d_in[12]};
  const float* asrc[3] = {(const float*)d_in[5], (const float*)d_in[9], (const float*)d_in[13]};
  const float* adst[3] = {(const float*)d_in[6], (const float*)d_in[10], (const float*)d_in[14]};
  const float* bias[3] = {(const float*)d_in[7], (const float*)d_in[11], (const float*)d_in[15]};
  const float* Wout = (const float*)d_in[16];
  const float* bout = (const float*)d_in[17];
  const float* vn_emb = (const float*)d_in[18];
  const float* Wm1 = (const float*)d_in[19];
  const float* bm1 = (const float*)d_in[20];
  const float* Wm2 = (const float*)d_in[21];
  const float* bm2 = (const float*)d_in[22];
  const float* Wf1 = (const float*)d_in[23];
  const float* bf1 = (const float*)d_in[24];
  const float* Wf2 = (const float*)d_in[25];
  const float* bf2 = (const float*)d_in[26];

  // workspace carve (all 4-byte types)
  float* h = (float*)d_ws;                  // N*64
  float* xa = h + (size_t)N * D;            // N*64
  float* s_src = xa + (size_t)N * D;        // N
  float* s_dst = s_src + N;                 // N
  int* deg = (int*)(s_dst + N);             // N
  int* row_ptr = deg + N;                   // N+1
  int* cursor = row_ptr + N + 1;            // N
  int* csr = cursor + N;                    // E+N

  const int ET = E + N;
  hipMemsetAsync(deg, 0, (size_t)N * sizeof(int), stream);
  hipMemsetAsync(cursor, 0, (size_t)N * sizeof(int), stream);
  hist_kernel<<<(ET + 255) / 256, 256, 0, stream>>>(ei, deg, E, N);
  scan_kernel<<<1, 1024, 0, stream>>>(deg, row_ptr, N);
  scatter_kernel<<<(ET + 255) / 256, 256, 0, stream>>>(ei, row_ptr, cursor, csr, E, N);

  const float* xin = x;
  for (int l = 0; l < 3; ++l) {
    project_kernel<<<1024, 256, 0, stream>>>(xin, W[l], asrc[l], adst[l], h, s_src, s_dst, N);
    aggregate_kernel<<<((size_t)N * 64 + 255) / 256, 256, 0, stream>>>(
        h, s_src, s_dst, row_ptr, csr, bias[l], xa, N);
    xin = xa;
  }

  out_project_kernel<<<1024, 256, 0, stream>>>(xa, Wout, bout, (float*)d_out, N);
  vn_kernel<<<G, 64, 0, stream>>>(xa, batch, N, vn_emb, Wm1, bm1, Wm2, bm2, Wf1, bf1, Wf2, bf2,
                                  (float*)d_out + (size_t)N * D);
}

// Round 2
// 1175.553 us; speedup vs baseline: 1.3141x; 1.3141x over previous
//
#include <hip/hip_runtime.h>

// GAT (3 layers, heads=1) + virtual-node MLP on MI355X.
// CSR build (hist/scan/scatter) -> per layer {project, aggregate}
// -> output GEMM + {wide segmented pool + tiny VN MLP}.

constexpr int D = 64;

__device__ __forceinline__ float lrelu(float v, float s) { return v >= 0.f ? v : v * s; }

// ---------------- CSR build ----------------

__global__ void hist_kernel(const int* __restrict__ ei, int* __restrict__ deg, int E, int N) {
  int i = blockIdx.x * blockDim.x + threadIdx.x;
  if (i >= E + N) return;
  int d = (i < E) ? ei[E + i] : (i - E);  // row 1 of edge_index = dst; self-loops appended
  atomicAdd(&deg[d], 1);
}

__global__ void scan_kernel(const int* __restrict__ deg, int* __restrict__ row_ptr, int n) {
  __shared__ int partial[1024];
  int t = threadIdx.x;
  int chunk = (n + 1023) >> 10;
  int beg = min(t * chunk, n);
  int end = min(beg + chunk, n);
  int s = 0;
  for (int i = beg; i < end; ++i) s += deg[i];
  partial[t] = s;
  __syncthreads();
  for (int off = 1; off < 1024; off <<= 1) {
    int v = (t >= off) ? partial[t - off] : 0;
    __syncthreads();
    partial[t] += v;
    __syncthreads();
  }
  int run = (t == 0) ? 0 : partial[t - 1];
  for (int i = beg; i < end; ++i) { row_ptr[i] = run; run += deg[i]; }
  if (end == n && beg < n) row_ptr[n] = run;
}

__global__ void scatter_kernel(const int* __restrict__ ei, const int* __restrict__ row_ptr,
                               int* __restrict__ cursor, int* __restrict__ csr, int E, int N) {
  int i = blockIdx.x * blockDim.x + threadIdx.x;
  if (i >= E + N) return;
  int s, d;
  if (i < E) { s = ei[i]; d = ei[E + i]; } else { s = d = i - E; }
  int pos = atomicAdd(&cursor[d], 1);
  csr[row_ptr[d] + pos] = s;
}

// ---------------- projection: h = x @ W, s_src = h.a_src, s_dst = h.a_dst ----------------

__global__ __launch_bounds__(256) void project_kernel(
    const float* __restrict__ x, const float* __restrict__ W,
    const float* __restrict__ a_src, const float* __restrict__ a_dst,
    float* __restrict__ h, float* __restrict__ s_src, float* __restrict__ s_dst, int N) {
  __shared__ float Wl[D * D];
  int t = threadIdx.x;
  for (int i = t; i < D * D; i += 256) Wl[i] = W[i];
  __syncthreads();
  int lane = t & 63;
  int warp = t >> 6;
  float asv = a_src[lane], adv = a_dst[lane];
  int w = blockIdx.x * 4 + warp;
  int nw = gridDim.x * 4;
  for (int r = w; r < N; r += nw) {
    float xv = x[(size_t)r * D + lane];
    float acc = 0.f;
#pragma unroll
    for (int k = 0; k < D; ++k) acc = fmaf(__shfl(xv, k), Wl[k * D + lane], acc);
    h[(size_t)r * D + lane] = acc;
    float ts = acc * asv, td = acc * adv;
#pragma unroll
    for (int off = 32; off; off >>= 1) { ts += __shfl_xor(ts, off); td += __shfl_xor(td, off); }
    if (lane == 0) { s_src[r] = ts; s_dst[r] = td; }
  }
}

// final projection with bias, no attention dots
__global__ __launch_bounds__(256) void out_project_kernel(
    const float* __restrict__ x, const float* __restrict__ W, const float* __restrict__ b,
    float* __restrict__ out, int N) {
  __shared__ float Wl[D * D];
  int t = threadIdx.x;
  for (int i = t; i < D * D; i += 256) Wl[i] = W[i];
  __syncthreads();
  int lane = t & 63;
  int warp = t >> 6;
  float bv = b[lane];
  int w = blockIdx.x * 4 + warp;
  int nw = gridDim.x * 4;
  for (int r = w; r < N; r += nw) {
    float xv = x[(size_t)r * D + lane];
    float acc = bv;
#pragma unroll
    for (int k = 0; k < D; ++k) acc = fmaf(__shfl(xv, k), Wl[k * D + lane], acc);
    out[(size_t)r * D + lane] = acc;
  }
}

// ---------------- fused attention softmax + weighted aggregation ----------------
// wave per dst node; lane = feature dim. alpha-normalization deferred to the end:
// out = (sum_j p_j h[src_j]) / (sum_j p_j + 1e-16) + b, then LeakyReLU(0.01).

__global__ __launch_bounds__(256) void aggregate_kernel(
    const float* __restrict__ h, const float* __restrict__ s_src, const float* __restrict__ s_dst,
    const int* __restrict__ row_ptr, const int* __restrict__ csr,
    const float* __restrict__ bias, float* __restrict__ xout, int N) {
  int w = (blockIdx.x * blockDim.x + threadIdx.x) >> 6;
  int lane = threadIdx.x & 63;
  if (w >= N) return;
  int beg = row_ptr[w], end = row_ptr[w + 1];
  float sd = s_dst[w];
  // pass 1: segment max of LeakyReLU(0.2) logits
  float m = -3.4e38f;
  for (int base = beg; base < end; base += 64) {
    int idx = base + lane;
    float e = -3.4e38f;
    if (idx < end) e = lrelu(s_src[csr[idx]] + sd, 0.2f);
    m = fmaxf(m, e);
  }
#pragma unroll
  for (int off = 32; off; off >>= 1) m = fmaxf(m, __shfl_xor(m, off));
  // pass 2: p = exp(e - m); acc += p * h[src]; denom += p
  float denom = 0.f, acc = 0.f;
  for (int base = beg; base < end; base += 64) {
    int idx = base + lane;
    int s = 0;
    float p = 0.f;
    if (idx < end) {
      s = csr[idx];
      p = __expf(lrelu(s_src[s] + sd, 0.2f) - m);
    }
    denom += p;
    int cnt = min(64, end - base);
    for (int k = 0; k < cnt; ++k) {
      float pk = __shfl(p, k);
      int sk = __shfl(s, k);
      acc = fmaf(pk, h[(size_t)sk * D + lane], acc);
    }
  }
#pragma unroll
  for (int off = 32; off; off >>= 1) denom += __shfl_xor(denom, off);
  float o = acc / (denom + 1e-16f) + bias[lane];
  xout[(size_t)w * D + lane] = lrelu(o, 0.01f);
}

// ---------------- virtual node ----------------
// batch is sorted: each wave owns a contiguous row chunk, keeps a running
// per-graph accumulator in registers, flushes one coalesced atomicAdd per
// graph boundary. pooled must be zeroed before launch.

__global__ __launch_bounds__(256) void pool_kernel(
    const float* __restrict__ xa, const int* __restrict__ batch, int N,
    float* __restrict__ pooled) {
  int lane = threadIdx.x & 63;
  int wid = (blockIdx.x * blockDim.x + threadIdx.x) >> 6;
  int nw = (gridDim.x * blockDim.x) >> 6;
  int chunk = (N + nw - 1) / nw;
  int beg = wid * chunk;
  int end = min(beg + chunk, N);
  if (beg >= end) return;
  int cur = batch[beg];
  float acc = 0.f;
  for (int r = beg; r < end; ++r) {
    int g = batch[r];
    if (g != cur) {
      atomicAdd(&pooled[(size_t)cur * D + lane], acc);
      acc = 0.f;
      cur = g;
    }
    acc += xa[(size_t)r * D + lane];
  }
  atomicAdd(&pooled[(size_t)cur * D + lane], acc);
}

__device__ __forceinline__ float mlp64(float v, const float* __restrict__ W,
                                       const float* __restrict__ b, int lane) {
  float u = b[lane];
#pragma unroll
  for (int k = 0; k < D; ++k) u = fmaf(__shfl(v, k), W[k * D + lane], u);
  return fmaxf(u, 0.f);
}

__global__ __launch_bounds__(64) void vn_mlp_kernel(
    const float* __restrict__ pooled, const float* __restrict__ vn_emb,
    const float* __restrict__ Wm1, const float* __restrict__ bm1,
    const float* __restrict__ Wm2, const float* __restrict__ bm2,
    const float* __restrict__ Wf1, const float* __restrict__ bf1,
    const float* __restrict__ Wf2, const float* __restrict__ bf2,
    float* __restrict__ out) {
  int g = blockIdx.x;
  int lane = threadIdx.x;
  float v = pooled[(size_t)g * D + lane] + vn_emb[lane];
  v = mlp64(v, Wm1, bm1, lane);
  v = mlp64(v, Wm2, bm2, lane);
  v = mlp64(v, Wf1, bf1, lane);
  v = mlp64(v, Wf2, bf2, lane);
  out[(size_t)g * D + lane] = v;
}

// ---------------- launch ----------------

extern "C" void kernel_launch(void* const* d_in, const int* in_sizes, int n_in,
                              void* d_out, int out_size, void* d_ws, size_t ws_size,
                              hipStream_t stream) {
  const float* x = (const float*)d_in[0];
  const int* ei = (const int*)d_in[1];
  const int* batch = (const int*)d_in[2];
  const int N = in_sizes[0] / D;
  const int E = in_sizes[1] / 2;
  const int G = 64;

  const float* W[3] = {(const float*)d_in[4], (const float*)d_in[8], (const float*)d_in[12]};
  const float* asrc[3] = {(const float*)d_in[5], (const float*)d_in[9], (const float*)d_in[13]};
  const float* adst[3] = {(const float*)d_in[6], (const float*)d_in[10], (const float*)d_in[14]};
  const float* bias[3] = {(const float*)d_in[7], (const float*)d_in[11], (const float*)d_in[15]};
  const float* Wout = (const float*)d_in[16];
  const float* bout = (const float*)d_in[17];
  const float* vn_emb = (const float*)d_in[18];
  const float* Wm1 = (const float*)d_in[19];
  const float* bm1 = (const float*)d_in[20];
  const float* Wm2 = (const float*)d_in[21];
  const float* bm2 = (const float*)d_in[22];
  const float* Wf1 = (const float*)d_in[23];
  const float* bf1 = (const float*)d_in[24];
  const float* Wf2 = (const float*)d_in[25];
  const float* bf2 = (const float*)d_in[26];

  // workspace carve (all 4-byte types)
  float* h = (float*)d_ws;                  // N*64
  float* xa = h + (size_t)N * D;            // N*64
  float* s_src = xa + (size_t)N * D;        // N
  float* s_dst = s_src + N;                 // N
  int* deg = (int*)(s_dst + N);             // N
  int* row_ptr = deg + N;                   // N+1
  int* cursor = row_ptr + N + 1;            // N
  int* csr = cursor + N;                    // E+N
  float* pooled = (float*)(csr + E + N);    // G*D

  const int ET = E + N;
  hipMemsetAsync(deg, 0, (size_t)N * sizeof(int), stream);
  hipMemsetAsync(cursor, 0, (size_t)N * sizeof(int), stream);
  hipMemsetAsync(pooled, 0, (size_t)G * D * sizeof(float), stream);
  hist_kernel<<<(ET + 255) / 256, 256, 0, stream>>>(ei, deg, E, N);
  scan_kernel<<<1, 1024, 0, stream>>>(deg, row_ptr, N);
  scatter_kernel<<<(ET + 255) / 256, 256, 0, stream>>>(ei, row_ptr, cursor, csr, E, N);

  const float* xin = x;
  for (int l = 0; l < 3; ++l) {
    project_kernel<<<1024, 256, 0, stream>>>(xin, W[l], asrc[l], adst[l], h, s_src, s_dst, N);
    aggregate_kernel<<<((size_t)N * 64 + 255) / 256, 256, 0, stream>>>(
        h, s_src, s_dst, row_ptr, csr, bias[l], xa, N);
    xin = xa;
  }

  out_project_kernel<<<1024, 256, 0, stream>>>(xa, Wout, bout, (float*)d_out, N);
  pool_kernel<<<512, 256, 0, stream>>>(xa, batch, N, pooled);
  vn_mlp_kernel<<<G, 64, 0, stream>>>(pooled, vn_emb, Wm1, bm1, Wm2, bm2, Wf1, bf1, Wf2, bf2,
                                      (float*)d_out + (size_t)N * D);
}

// Round 4
// 1028.899 us; speedup vs baseline: 1.5014x; 1.1425x over previous
//
#include <hip/hip_runtime.h>

// GAT (3 layers, heads=1) + virtual-node MLP on MI355X.
// CSR build (hist / hierarchical scan / scatter) -> per layer {project, aggregate}
// -> output GEMM + {wide segmented pool + tiny VN MLP}.

constexpr int D = 64;

__device__ __forceinline__ float lrelu(float v, float s) { return v >= 0.f ? v : v * s; }

// ---------------- CSR build ----------------

__global__ void hist_kernel(const int* __restrict__ ei, int* __restrict__ deg, int E, int N) {
  int i = blockIdx.x * blockDim.x + threadIdx.x;
  if (i >= E + N) return;
  int d = (i < E) ? ei[E + i] : (i - E);  // row 1 of edge_index = dst; self-loops appended
  atomicAdd(&deg[d], 1);
}

// hierarchical scan: per-block sums -> scan of block sums -> per-block exclusive scan
__global__ __launch_bounds__(256) void block_sum_kernel(const int* __restrict__ deg,
                                                        int* __restrict__ blk, int n) {
  int t = threadIdx.x;
  int i = blockIdx.x * 256 + t;
  int v = (i < n) ? deg[i] : 0;
#pragma unroll
  for (int off = 32; off; off >>= 1) v += __shfl_xor(v, off);
  __shared__ int ws[4];
  if ((t & 63) == 0) ws[t >> 6] = v;
  __syncthreads();
  if (t == 0) blk[blockIdx.x] = ws[0] + ws[1] + ws[2] + ws[3];
}

__global__ __launch_bounds__(1024) void blk_scan_kernel(int* __restrict__ blk,
                                                        int* __restrict__ blk_off, int nb) {
  __shared__ int s[1024];
  int t = threadIdx.x;
  int v = (t < nb) ? blk[t] : 0;
  s[t] = v;
  __syncthreads();
  for (int off = 1; off < 1024; off <<= 1) {
    int u = (t >= off) ? s[t - off] : 0;
    __syncthreads();
    s[t] += u;
    __syncthreads();
  }
  if (t < nb) blk_off[t] = s[t] - v;  // exclusive
}

__global__ __launch_bounds__(256) void row_ptr_kernel(const int* __restrict__ deg,
                                                      const int* __restrict__ blk_off,
                                                      int* __restrict__ row_ptr, int n) {
  int t = threadIdx.x;
  int lane = t & 63;
  int w = t >> 6;
  int i = blockIdx.x * 256 + t;
  int v = (i < n) ? deg[i] : 0;
  int inc = v;
#pragma unroll
  for (int off = 1; off < 64; off <<= 1) {
    int u = __shfl_up(inc, off);
    if (lane >= off) inc += u;
  }
  __shared__ int wsum[4];
  if (lane == 63) wsum[w] = inc;
  __syncthreads();
  int woff = 0;
  for (int k = 0; k < w; ++k) woff += wsum[k];
  int ex = blk_off[blockIdx.x] + woff + inc - v;
  if (i < n) row_ptr[i] = ex;
  if (i == n - 1) row_ptr[n] = ex + v;
}

__global__ void scatter_kernel(const int* __restrict__ ei, const int* __restrict__ row_ptr,
                               int* __restrict__ cursor, int* __restrict__ csr, int E, int N) {
  int i = blockIdx.x * blockDim.x + threadIdx.x;
  if (i >= E + N) return;
  int s, d;
  if (i < E) { s = ei[i]; d = ei[E + i]; } else { s = d = i - E; }
  int pos = atomicAdd(&cursor[d], 1);
  csr[row_ptr[d] + pos] = s;
}

// ---------------- projection: h = x @ W, s_src = h.a_src, s_dst = h.a_dst ----------------

__global__ __launch_bounds__(256) void project_kernel(
    const float* __restrict__ x, const float* __restrict__ W,
    const float* __restrict__ a_src, const float* __restrict__ a_dst,
    float* __restrict__ h, float* __restrict__ s_src, float* __restrict__ s_dst, int N) {
  __shared__ float Wl[D * D];
  int t = threadIdx.x;
  for (int i = t; i < D * D; i += 256) Wl[i] = W[i];
  __syncthreads();
  int lane = t & 63;
  int warp = t >> 6;
  float asv = a_src[lane], adv = a_dst[lane];
  int w = blockIdx.x * 4 + warp;
  int nw = gridDim.x * 4;
  for (int r = w; r < N; r += nw) {
    float xv = x[(size_t)r * D + lane];
    float acc = 0.f;
#pragma unroll
    for (int k = 0; k < D; ++k) acc = fmaf(__shfl(xv, k), Wl[k * D + lane], acc);
    h[(size_t)r * D + lane] = acc;
    float ts = acc * asv, td = acc * adv;
#pragma unroll
    for (int off = 32; off; off >>= 1) { ts += __shfl_xor(ts, off); td += __shfl_xor(td, off); }
    if (lane == 0) { s_src[r] = ts; s_dst[r] = td; }
  }
}

// final projection with bias, no attention dots
__global__ __launch_bounds__(256) void out_project_kernel(
    const float* __restrict__ x, const float* __restrict__ W, const float* __restrict__ b,
    float* __restrict__ out, int N) {
  __shared__ float Wl[D * D];
  int t = threadIdx.x;
  for (int i = t; i < D * D; i += 256) Wl[i] = W[i];
  __syncthreads();
  int lane = t & 63;
  int warp = t >> 6;
  float bv = b[lane];
  int w = blockIdx.x * 4 + warp;
  int nw = gridDim.x * 4;
  for (int r = w; r < N; r += nw) {
    float xv = x[(size_t)r * D + lane];
    float acc = bv;
#pragma unroll
    for (int k = 0; k < D; ++k) acc = fmaf(__shfl(xv, k), Wl[k * D + lane], acc);
    out[(size_t)r * D + lane] = acc;
  }
}

// ---------------- fused attention softmax + weighted aggregation ----------------
// wave per dst node; lane = feature dim. alpha-normalization deferred to the end:
// out = (sum_j p_j h[src_j]) / (sum_j p_j + 1e-16) + b, then LeakyReLU(0.01).

__global__ __launch_bounds__(256) void aggregate_kernel(
    const float* __restrict__ h, const float* __restrict__ s_src, const float* __restrict__ s_dst,
    const int* __restrict__ row_ptr, const int* __restrict__ csr,
    const float* __restrict__ bias, float* __restrict__ xout, int N) {
  int w = (blockIdx.x * blockDim.x + threadIdx.x) >> 6;
  int lane = threadIdx.x & 63;
  if (w >= N) return;
  int beg = row_ptr[w], end = row_ptr[w + 1];
  float sd = s_dst[w];
  // pass 1: segment max of LeakyReLU(0.2) logits
  float m = -3.4e38f;
  for (int base = beg; base < end; base += 64) {
    int idx = base + lane;
    float e = -3.4e38f;
    if (idx < end) e = lrelu(s_src[csr[idx]] + sd, 0.2f);
    m = fmaxf(m, e);
  }
#pragma unroll
  for (int off = 32; off; off >>= 1) m = fmaxf(m, __shfl_xor(m, off));
  // pass 2: p = exp(e - m); acc += p * h[src]; denom += p
  float denom = 0.f, acc = 0.f;
  for (int base = beg; base < end; base += 64) {
    int idx = base + lane;
    int s = 0;
    float p = 0.f;
    if (idx < end) {
      s = csr[idx];
      p = __expf(lrelu(s_src[s] + sd, 0.2f) - m);
    }
    denom += p;
    int cnt = min(64, end - base);
    for (int k = 0; k < cnt; ++k) {
      float pk = __shfl(p, k);
      int sk = __shfl(s, k);
      acc = fmaf(pk, h[(size_t)sk * D + lane], acc);
    }
  }
#pragma unroll
  for (int off = 32; off; off >>= 1) denom += __shfl_xor(denom, off);
  float o = acc / (denom + 1e-16f) + bias[lane];
  xout[(size_t)w * D + lane] = lrelu(o, 0.01f);
}

// ---------------- virtual node ----------------
// batch is sorted: each wave owns a contiguous row chunk, keeps a running
// per-graph accumulator in registers, flushes one coalesced atomicAdd per
// graph boundary. pooled must be zeroed before launch.

__global__ __launch_bounds__(256) void pool_kernel(
    const float* __restrict__ xa, const int* __restrict__ batch, int N,
    float* __restrict__ pooled) {
  int lane = threadIdx.x & 63;
  int wid = (blockIdx.x * blockDim.x + threadIdx.x) >> 6;
  int nw = (gridDim.x * blockDim.x) >> 6;
  int chunk = (N + nw - 1) / nw;
  int beg = wid * chunk;
  int end = min(beg + chunk, N);
  if (beg >= end) return;
  int cur = batch[beg];
  float acc = 0.f;
  for (int r = beg; r < end; ++r) {
    int g = batch[r];
    if (g != cur) {
      atomicAdd(&pooled[(size_t)cur * D + lane], acc);
      acc = 0.f;
      cur = g;
    }
    acc += xa[(size_t)r * D + lane];
  }
  atomicAdd(&pooled[(size_t)cur * D + lane], acc);
}

__device__ __forceinline__ float mlp64(float v, const float* __restrict__ W,
                                       const float* __restrict__ b, int lane) {
  float u = b[lane];
#pragma unroll
  for (int k = 0; k < D; ++k) u = fmaf(__shfl(v, k), W[k * D + lane], u);
  return fmaxf(u, 0.f);
}

__global__ __launch_bounds__(64) void vn_mlp_kernel(
    const float* __restrict__ pooled, const float* __restrict__ vn_emb,
    const float* __restrict__ Wm1, const float* __restrict__ bm1,
    const float* __restrict__ Wm2, const float* __restrict__ bm2,
    const float* __restrict__ Wf1, const float* __restrict__ bf1,
    const float* __restrict__ Wf2, const float* __restrict__ bf2,
    float* __restrict__ out) {
  int g = blockIdx.x;
  int lane = threadIdx.x;
  float v = pooled[(size_t)g * D + lane] + vn_emb[lane];
  v = mlp64(v, Wm1, bm1, lane);
  v = mlp64(v, Wm2, bm2, lane);
  v = mlp64(v, Wf1, bf1, lane);
  v = mlp64(v, Wf2, bf2, lane);
  out[(size_t)g * D + lane] = v;
}

// ---------------- launch ----------------

extern "C" void kernel_launch(void* const* d_in, const int* in_sizes, int n_in,
                              void* d_out, int out_size, void* d_ws, size_t ws_size,
                              hipStream_t stream) {
  const float* x = (const float*)d_in[0];
  const int* ei = (const int*)d_in[1];
  const int* batch = (const int*)d_in[2];
  const int N = in_sizes[0] / D;
  const int E = in_sizes[1] / 2;
  const int G = 64;

  const float* W[3] = {(const float*)d_in[4], (const float*)d_in[8], (const float*)d_in[12]};
  const float* asrc[3] = {(const float*)d_in[5], (const float*)d_in[9], (const float*)d_in[13]};
  const float* adst[3] = {(const float*)d_in[6], (const float*)d_in[10], (const float*)d_in[14]};
  const float* bias[3] = {(const float*)d_in[7], (const float*)d_in[11], (const float*)d_in[15]};
  const float* Wout = (const float*)d_in[16];
  const float* bout = (const float*)d_in[17];
  const float* vn_emb = (const float*)d_in[18];
  const float* Wm1 = (const float*)d_in[19];
  const float* bm1 = (const float*)d_in[20];
  const float* Wm2 = (const float*)d_in[21];
  const float* bm2 = (const float*)d_in[22];
  const float* Wf1 = (const float*)d_in[23];
  const float* bf1 = (const float*)d_in[24];
  const float* Wf2 = (const float*)d_in[25];
  const float* bf2 = (const float*)d_in[26];

  // workspace carve (all 4-byte types)
  float* h = (float*)d_ws;                  // N*64
  float* xa = h + (size_t)N * D;            // N*64
  float* s_src = xa + (size_t)N * D;        // N
  float* s_dst = s_src + N;                 // N
  int* deg = (int*)(s_dst + N);             // N
  int* row_ptr = deg + N;                   // N+1
  int* cursor = row_ptr + N + 1;            // N
  int* csr = cursor + N;                    // E+N
  float* pooled = (float*)(csr + E + N);    // G*D
  int* blk = (int*)(pooled + (size_t)G * D);  // nb
  int* blk_off = blk + 1024;                  // nb

  const int ET = E + N;
  const int nb = (N + 255) / 256;  // 391 <= 1024
  hipMemsetAsync(deg, 0, (size_t)N * sizeof(int), stream);
  hipMemsetAsync(cursor, 0, (size_t)N * sizeof(int), stream);
  hipMemsetAsync(pooled, 0, (size_t)G * D * sizeof(float), stream);
  hist_kernel<<<(ET + 255) / 256, 256, 0, stream>>>(ei, deg, E, N);
  block_sum_kernel<<<nb, 256, 0, stream>>>(deg, blk, N);
  blk_scan_kernel<<<1, 1024, 0, stream>>>(blk, blk_off, nb);
  row_ptr_kernel<<<nb, 256, 0, stream>>>(deg, blk_off, row_ptr, N);
  scatter_kernel<<<(ET + 255) / 256, 256, 0, stream>>>(ei, row_ptr, cursor, csr, E, N);

  const float* xin = x;
  for (int l = 0; l < 3; ++l) {
    project_kernel<<<1024, 256, 0, stream>>>(xin, W[l], asrc[l], adst[l], h, s_src, s_dst, N);
    aggregate_kernel<<<((size_t)N * 64 + 255) / 256, 256, 0, stream>>>(
        h, s_src, s_dst, row_ptr, csr, bias[l], xa, N);
    xin = xa;
  }

  out_project_kernel<<<1024, 256, 0, stream>>>(xa, Wout, bout, (float*)d_out, N);
  pool_kernel<<<512, 256, 0, stream>>>(xa, batch, N, pooled);
  vn_mlp_kernel<<<G, 64, 0, stream>>>(pooled, vn_emb, Wm1, bm1, Wm2, bm2, Wf1, bf1, Wf2, bf2,
                                      (float*)d_out + (size_t)N * D);
}

// Round 5
// 784.664 us; speedup vs baseline: 1.9687x; 1.3113x over previous
//
#include <hip/hip_runtime.h>

// GAT (3 layers, heads=1) + virtual-node MLP on MI355X.
// CSR build (hist / hierarchical scan / scatter) -> per layer {project, aggregate}
// -> output GEMM + {wide segmented pool + tiny VN MLP}.
// Aggregate: 4 nodes/wave (16 lanes each), online softmax, bf16 h gather.

constexpr int D = 64;

__device__ __forceinline__ float lrelu(float v, float s) { return v >= 0.f ? v : v * s; }

__device__ __forceinline__ unsigned short f2bf(float f) {
  unsigned u = __float_as_uint(f);
  return (unsigned short)((u + 0x7FFFu + ((u >> 16) & 1u)) >> 16);
}
__device__ __forceinline__ float bf2f(unsigned short b) {
  return __uint_as_float((unsigned)b << 16);
}

// ---------------- CSR build ----------------

__global__ void hist_kernel(const int* __restrict__ ei, int* __restrict__ deg, int E, int N) {
  int i = blockIdx.x * blockDim.x + threadIdx.x;
  if (i >= E + N) return;
  int d = (i < E) ? ei[E + i] : (i - E);  // row 1 of edge_index = dst; self-loops appended
  atomicAdd(&deg[d], 1);
}

// hierarchical scan: per-block sums -> scan of block sums -> per-block exclusive scan
__global__ __launch_bounds__(256) void block_sum_kernel(const int* __restrict__ deg,
                                                        int* __restrict__ blk, int n) {
  int t = threadIdx.x;
  int i = blockIdx.x * 256 + t;
  int v = (i < n) ? deg[i] : 0;
#pragma unroll
  for (int off = 32; off; off >>= 1) v += __shfl_xor(v, off);
  __shared__ int ws[4];
  if ((t & 63) == 0) ws[t >> 6] = v;
  __syncthreads();
  if (t == 0) blk[blockIdx.x] = ws[0] + ws[1] + ws[2] + ws[3];
}

__global__ __launch_bounds__(1024) void blk_scan_kernel(int* __restrict__ blk,
                                                        int* __restrict__ blk_off, int nb) {
  __shared__ int s[1024];
  int t = threadIdx.x;
  int v = (t < nb) ? blk[t] : 0;
  s[t] = v;
  __syncthreads();
  for (int off = 1; off < 1024; off <<= 1) {
    int u = (t >= off) ? s[t - off] : 0;
    __syncthreads();
    s[t] += u;
    __syncthreads();
  }
  if (t < nb) blk_off[t] = s[t] - v;  // exclusive
}

__global__ __launch_bounds__(256) void row_ptr_kernel(const int* __restrict__ deg,
                                                      const int* __restrict__ blk_off,
                                                      int* __restrict__ row_ptr, int n) {
  int t = threadIdx.x;
  int lane = t & 63;
  int w = t >> 6;
  int i = blockIdx.x * 256 + t;
  int v = (i < n) ? deg[i] : 0;
  int inc = v;
#pragma unroll
  for (int off = 1; off < 64; off <<= 1) {
    int u = __shfl_up(inc, off);
    if (lane >= off) inc += u;
  }
  __shared__ int wsum[4];
  if (lane == 63) wsum[w] = inc;
  __syncthreads();
  int woff = 0;
  for (int k = 0; k < w; ++k) woff += wsum[k];
  int ex = blk_off[blockIdx.x] + woff + inc - v;
  if (i < n) row_ptr[i] = ex;
  if (i == n - 1) row_ptr[n] = ex + v;
}

__global__ void scatter_kernel(const int* __restrict__ ei, const int* __restrict__ row_ptr,
                               int* __restrict__ cursor, int* __restrict__ csr, int E, int N) {
  int i = blockIdx.x * blockDim.x + threadIdx.x;
  if (i >= E + N) return;
  int s, d;
  if (i < E) { s = ei[i]; d = ei[E + i]; } else { s = d = i - E; }
  int pos = atomicAdd(&cursor[d], 1);
  csr[row_ptr[d] + pos] = s;
}

// ---------------- projection: h_bf = bf16(x @ W), s_src = h.a_src, s_dst = h.a_dst ----------------

__global__ __launch_bounds__(256) void project_kernel(
    const float* __restrict__ x, const float* __restrict__ W,
    const float* __restrict__ a_src, const float* __restrict__ a_dst,
    unsigned short* __restrict__ h_bf, float* __restrict__ s_src, float* __restrict__ s_dst,
    int N) {
  __shared__ float Wl[D * D];
  int t = threadIdx.x;
  for (int i = t; i < D * D; i += 256) Wl[i] = W[i];
  __syncthreads();
  int lane = t & 63;
  int warp = t >> 6;
  float asv = a_src[lane], adv = a_dst[lane];
  int w = blockIdx.x * 4 + warp;
  int nw = gridDim.x * 4;
  for (int r = w; r < N; r += nw) {
    float xv = x[(size_t)r * D + lane];
    float acc = 0.f;
#pragma unroll
    for (int k = 0; k < D; ++k) acc = fmaf(__shfl(xv, k), Wl[k * D + lane], acc);
    h_bf[(size_t)r * D + lane] = f2bf(acc);
    float ts = acc * asv, td = acc * adv;
#pragma unroll
    for (int off = 32; off; off >>= 1) { ts += __shfl_xor(ts, off); td += __shfl_xor(td, off); }
    if (lane == 0) { s_src[r] = ts; s_dst[r] = td; }
  }
}

// final projection with bias, no attention dots (f32 in, f32 out)
__global__ __launch_bounds__(256) void out_project_kernel(
    const float* __restrict__ x, const float* __restrict__ W, const float* __restrict__ b,
    float* __restrict__ out, int N) {
  __shared__ float Wl[D * D];
  int t = threadIdx.x;
  for (int i = t; i < D * D; i += 256) Wl[i] = W[i];
  __syncthreads();
  int lane = t & 63;
  int warp = t >> 6;
  float bv = b[lane];
  int w = blockIdx.x * 4 + warp;
  int nw = gridDim.x * 4;
  for (int r = w; r < N; r += nw) {
    float xv = x[(size_t)r * D + lane];
    float acc = bv;
#pragma unroll
    for (int k = 0; k < D; ++k) acc = fmaf(__shfl(xv, k), Wl[k * D + lane], acc);
    out[(size_t)r * D + lane] = acc;
  }
}

// ---------------- fused attention: online softmax + weighted aggregation ----------------
// 4 nodes per wave, 16 lanes per node (lane l owns features 4l..4l+3).
// Flash-style single pass: running max m, denom, acc with rescale per 16-edge chunk.
// out = acc/denom + b, then LeakyReLU(0.01). Stored f32 (float4/lane).

__global__ __launch_bounds__(256) void aggregate_kernel(
    const unsigned short* __restrict__ h_bf, const float* __restrict__ s_src,
    const float* __restrict__ s_dst, const int* __restrict__ row_ptr,
    const int* __restrict__ csr, const float* __restrict__ bias,
    float* __restrict__ xout, int N) {
  int lane = threadIdx.x & 63;
  int l = lane & 15;
  int gbase = lane & 48;
  int wid = (blockIdx.x * blockDim.x + threadIdx.x) >> 6;
  int node = wid * 4 + (lane >> 4);
  if (node >= N) return;
  int beg = row_ptr[node], end = row_ptr[node + 1];
  float sd = s_dst[node];
  const ushort4* hb4 = (const ushort4*)h_bf;
  float4 bv = ((const float4*)bias)[l];

  float m = -3.4e38f;
  float denom = 0.f;
  float4 acc = {0.f, 0.f, 0.f, 0.f};
  for (int base = beg; base < end; base += 16) {
    int idx = base + l;
    bool valid = idx < end;
    int s = valid ? csr[idx] : 0;
    float e = valid ? lrelu(s_src[s] + sd, 0.2f) : -3.4e38f;
    // group max / new running max
    float mc = e;
#pragma unroll
    for (int off = 8; off; off >>= 1) mc = fmaxf(mc, __shfl_xor(mc, off));
    float mn = fmaxf(m, mc);
    float scale = __expf(m - mn);  // m==-3.4e38 -> 0
    float p = valid ? __expf(e - mn) : 0.f;
    float ps = p;
#pragma unroll
    for (int off = 8; off; off >>= 1) ps += __shfl_xor(ps, off);
    denom = denom * scale + ps;
    acc.x *= scale; acc.y *= scale; acc.z *= scale; acc.w *= scale;
    m = mn;
    // weighted accumulation; invalid slots have p==0 (s==0 load is L1-hot, harmless)
#pragma unroll
    for (int k = 0; k < 16; ++k) {
      float pk = __shfl(p, gbase | k);
      int sk = __shfl(s, gbase | k);
      ushort4 hb = hb4[(size_t)sk * 16 + l];
      acc.x = fmaf(pk, bf2f(hb.x), acc.x);
      acc.y = fmaf(pk, bf2f(hb.y), acc.y);
      acc.z = fmaf(pk, bf2f(hb.z), acc.z);
      acc.w = fmaf(pk, bf2f(hb.w), acc.w);
    }
  }
  float inv = 1.f / (denom + 1e-16f);
  float4 o;
  o.x = lrelu(fmaf(acc.x, inv, bv.x), 0.01f);
  o.y = lrelu(fmaf(acc.y, inv, bv.y), 0.01f);
  o.z = lrelu(fmaf(acc.z, inv, bv.z), 0.01f);
  o.w = lrelu(fmaf(acc.w, inv, bv.w), 0.01f);
  ((float4*)xout)[(size_t)node * 16 + l] = o;
}

// ---------------- virtual node ----------------
// batch is sorted: each wave owns a contiguous row chunk, keeps a running
// per-graph accumulator in registers, flushes one coalesced atomicAdd per
// graph boundary. pooled must be zeroed before launch.

__global__ __launch_bounds__(256) void pool_kernel(
    const float* __restrict__ xa, const int* __restrict__ batch, int N,
    float* __restrict__ pooled) {
  int lane = threadIdx.x & 63;
  int wid = (blockIdx.x * blockDim.x + threadIdx.x) >> 6;
  int nw = (gridDim.x * blockDim.x) >> 6;
  int chunk = (N + nw - 1) / nw;
  int beg = wid * chunk;
  int end = min(beg + chunk, N);
  if (beg >= end) return;
  int cur = batch[beg];
  float acc = 0.f;
  for (int r = beg; r < end; ++r) {
    int g = batch[r];
    if (g != cur) {
      atomicAdd(&pooled[(size_t)cur * D + lane], acc);
      acc = 0.f;
      cur = g;
    }
    acc += xa[(size_t)r * D + lane];
  }
  atomicAdd(&pooled[(size_t)cur * D + lane], acc);
}

__device__ __forceinline__ float mlp64(float v, const float* __restrict__ W,
                                       const float* __restrict__ b, int lane) {
  float u = b[lane];
#pragma unroll
  for (int k = 0; k < D; ++k) u = fmaf(__shfl(v, k), W[k * D + lane], u);
  return fmaxf(u, 0.f);
}

__global__ __launch_bounds__(64) void vn_mlp_kernel(
    const float* __restrict__ pooled, const float* __restrict__ vn_emb,
    const float* __restrict__ Wm1, const float* __restrict__ bm1,
    const float* __restrict__ Wm2, const float* __restrict__ bm2,
    const float* __restrict__ Wf1, const float* __restrict__ bf1,
    const float* __restrict__ Wf2, const float* __restrict__ bf2,
    float* __restrict__ out) {
  int g = blockIdx.x;
  int lane = threadIdx.x;
  float v = pooled[(size_t)g * D + lane] + vn_emb[lane];
  v = mlp64(v, Wm1, bm1, lane);
  v = mlp64(v, Wm2, bm2, lane);
  v = mlp64(v, Wf1, bf1, lane);
  v = mlp64(v, Wf2, bf2, lane);
  out[(size_t)g * D + lane] = v;
}

// ---------------- launch ----------------

extern "C" void kernel_launch(void* const* d_in, const int* in_sizes, int n_in,
                              void* d_out, int out_size, void* d_ws, size_t ws_size,
                              hipStream_t stream) {
  const float* x = (const float*)d_in[0];
  const int* ei = (const int*)d_in[1];
  const int* batch = (const int*)d_in[2];
  const int N = in_sizes[0] / D;
  const int E = in_sizes[1] / 2;
  const int G = 64;

  const float* W[3] = {(const float*)d_in[4], (const float*)d_in[8], (const float*)d_in[12]};
  const float* asrc[3] = {(const float*)d_in[5], (const float*)d_in[9], (const float*)d_in[13]};
  const float* adst[3] = {(const float*)d_in[6], (const float*)d_in[10], (const float*)d_in[14]};
  const float* bias[3] = {(const float*)d_in[7], (const float*)d_in[11], (const float*)d_in[15]};
  const float* Wout = (const float*)d_in[16];
  const float* bout = (const float*)d_in[17];
  const float* vn_emb = (const float*)d_in[18];
  const float* Wm1 = (const float*)d_in[19];
  const float* bm1 = (const float*)d_in[20];
  const float* Wm2 = (const float*)d_in[21];
  const float* bm2 = (const float*)d_in[22];
  const float* Wf1 = (const float*)d_in[23];
  const float* bf1 = (const float*)d_in[24];
  const float* Wf2 = (const float*)d_in[25];
  const float* bf2 = (const float*)d_in[26];

  // workspace carve
  unsigned short* h_bf = (unsigned short*)d_ws;        // N*64 bf16
  float* xa = (float*)(h_bf + (size_t)N * D);          // N*64 f32
  float* s_src = xa + (size_t)N * D;                   // N
  float* s_dst = s_src + N;                            // N
  int* deg = (int*)(s_dst + N);                        // N
  int* row_ptr = deg + N;                              // N+1
  int* cursor = row_ptr + N + 1;                       // N
  int* csr = cursor + N;                               // E+N
  float* pooled = (float*)(csr + E + N);               // G*D
  int* blk = (int*)(pooled + (size_t)G * D);           // nb
  int* blk_off = blk + 1024;                           // nb

  const int ET = E + N;
  const int nb = (N + 255) / 256;  // 391 <= 1024
  hipMemsetAsync(deg, 0, (size_t)N * sizeof(int), stream);
  hipMemsetAsync(cursor, 0, (size_t)N * sizeof(int), stream);
  hipMemsetAsync(pooled, 0, (size_t)G * D * sizeof(float), stream);
  hist_kernel<<<(ET + 255) / 256, 256, 0, stream>>>(ei, deg, E, N);
  block_sum_kernel<<<nb, 256, 0, stream>>>(deg, blk, N);
  blk_scan_kernel<<<1, 1024, 0, stream>>>(blk, blk_off, nb);
  row_ptr_kernel<<<nb, 256, 0, stream>>>(deg, blk_off, row_ptr, N);
  scatter_kernel<<<(ET + 255) / 256, 256, 0, stream>>>(ei, row_ptr, cursor, csr, E, N);

  const float* xin = x;
  for (int l = 0; l < 3; ++l) {
    project_kernel<<<1024, 256, 0, stream>>>(xin, W[l], asrc[l], adst[l], h_bf, s_src, s_dst, N);
    aggregate_kernel<<<(N + 15) / 16, 256, 0, stream>>>(
        h_bf, s_src, s_dst, row_ptr, csr, bias[l], xa, N);
    xin = xa;
  }

  out_project_kernel<<<1024, 256, 0, stream>>>(xa, Wout, bout, (float*)d_out, N);
  pool_kernel<<<512, 256, 0, stream>>>(xa, batch, N, pooled);
  vn_mlp_kernel<<<G, 64, 0, stream>>>(pooled, vn_emb, Wm1, bm1, Wm2, bm2, Wf1, bf1, Wf2, bf2,
                                      (float*)d_out + (size_t)N * D);
}